// Round 1
// baseline (347.109 us; speedup 1.0000x reference)
//
#include <hip/hip_runtime.h>

// GraphAttention (e3nn-style) on MI355X — Round 5: kill the LDS-broadcast wall.
// Round-4 counters: edge_v_a 111 µs with VALUBusy 20%, HBM 2%, MfmaUtil 0,
// 0 bank conflicts -> time goes to wave-uniform ds_read_b128 weight broadcasts
// (16 B/instr, ~12 cyc): 3072 reads/wave = ~94 µs of pure LDS issue.
// Fix: (a) weights stored bf16 in LDS (half the ds_read instructions; unpack is
// 1 VALU op/weight and VALU was 20% busy), (b) 2 edges per thread so one weight
// sweep serves 128 edges/wave. => 4x fewer weight-read cycles per edge.
// Precision hedge: edge_v_a stages xs as f32 (pre-scaled by shs) so the
// dominant scalar-output path keeps exactly one bf16-rounded factor (as before).
//
// Dims: M0=16 M1=8 Q0=8 Q1=4 O0=16 O1=8 EDGE_BASIS=16 HIDDEN=32
// TPK [32][320]: w1[0,128) w2[128,192) w3[192,256) w4[256,288) w5[288,320)
// TPV [32][640]: w1[0,256) w2[256,384) w3[384,512) w4[512,576) w5[576,640)
//
// Pipeline: node_pre | count_edges | scan | edge_k | edge_v_a | edge_v_b | node_reduce
// ws (4B units): qd[N*20] | cnt[N] | start[N+1] | cursor[N] | flag | pad |
//                exbuf[E] | sabuf[E] | posbuf[E] | vbuf[E*40]

#define BS 256           // threads per block (edge kernels)
#define EPB 512          // edges per block (2 per thread: e0=base+tid, e1=e0+BS)

__device__ __forceinline__ float silu_f(float x) {
    return x * (1.0f / (1.0f + __expf(-x)));
}
__device__ __forceinline__ unsigned short f2b(float f) {   // f32 -> bf16 (RNE)
    unsigned u = __float_as_uint(f);
    u += 0x7fffu + ((u >> 16) & 1u);
    return (unsigned short)(u >> 16);
}
__device__ __forceinline__ float bl(unsigned u) {          // low bf16 -> f32
    return __uint_as_float(u << 16);
}
__device__ __forceinline__ float bh(unsigned u) {          // high bf16 -> f32
    return __uint_as_float(u & 0xffff0000u);
}
__device__ __forceinline__ unsigned pk2(float a, float b) { // pack 2 bf16
    return (unsigned)f2b(a) | ((unsigned)f2b(b) << 16);
}
__device__ __forceinline__ void up8(const uint4 a, float* w) {
    w[0] = bl(a.x); w[1] = bh(a.x); w[2] = bl(a.y); w[3] = bh(a.y);
    w[4] = bl(a.z); w[5] = bh(a.z); w[6] = bl(a.w); w[7] = bh(a.w);
}
__device__ __forceinline__ void up4(const uint2 a, float* w) {
    w[0] = bl(a.x); w[1] = bh(a.x); w[2] = bl(a.y); w[3] = bh(a.y);
}

__global__ __launch_bounds__(256) void node_pre(
    const float* __restrict__ node_ft,
    const int*   __restrict__ ei,
    const float* __restrict__ w_q_s, const float* __restrict__ w_q_v,
    const float* __restrict__ wdot_s, const float* __restrict__ wdot_v,
    float* __restrict__ qd, int* __restrict__ cnt, int* __restrict__ flag,
    int N, int E)
{
    const int n = blockIdx.x * blockDim.x + threadIdx.x;
    if (n == 0) {
        int acc = 0;
        const int kmax = (E < 64) ? E : 64;
        for (int k = 0; k < kmax; ++k) acc |= ei[2*k + 1];
        *flag = (acc == 0) ? 1 : 0;   // int64 layout => odd words all zero
    }
    if (n >= N) return;
    cnt[n] = 0;

    const float* nf = node_ft + (size_t)n * 40;
    float xs[16];
#pragma unroll
    for (int i = 0; i < 16; ++i) xs[i] = nf[i];
    float q[8];
#pragma unroll
    for (int o = 0; o < 8; ++o) {
        float a = 0.f;
#pragma unroll
        for (int i = 0; i < 16; ++i) a += xs[i] * w_q_s[i*8 + o];
        q[o] = a * 0.25f;
    }
    float* qdn = qd + (size_t)n * 20;
#pragma unroll
    for (int j = 0; j < 8; ++j) {
        float a = 0.f;
#pragma unroll
        for (int i = 0; i < 8; ++i) a += q[i] * wdot_s[i*8 + j];
        qdn[j] = a;
    }
    float xv[8][3];
#pragma unroll
    for (int i = 0; i < 8; ++i)
#pragma unroll
        for (int c = 0; c < 3; ++c) xv[i][c] = nf[16 + i*3 + c];
    float qv[4][3];
#pragma unroll
    for (int o = 0; o < 4; ++o)
#pragma unroll
        for (int c = 0; c < 3; ++c) {
            float a = 0.f;
#pragma unroll
            for (int i = 0; i < 8; ++i) a += xv[i][c] * w_q_v[i*4 + o];
            qv[o][c] = a * 0.35355339059327379f;
        }
#pragma unroll
    for (int j = 0; j < 4; ++j)
#pragma unroll
        for (int c = 0; c < 3; ++c) {
            float a = 0.f;
#pragma unroll
            for (int i = 0; i < 4; ++i) a += qv[i][c] * wdot_v[i*4 + j];
            qdn[8 + j*3 + c] = a;
        }
}

__global__ __launch_bounds__(256) void count_edges(
    const int* __restrict__ ei, int* __restrict__ cnt,
    const int* __restrict__ flag, int E)
{
    const int e = blockIdx.x * blockDim.x + threadIdx.x;
    if (e >= E) return;
    const int is64 = *flag;
    const int rcv = is64 ? ei[2*(E + e)] : ei[E + e];
    atomicAdd(cnt + rcv, 1);
}

// 1 block, 1024 threads; shuffle-based scan (few barriers).
__global__ __launch_bounds__(1024) void scan_kernel(
    const int* __restrict__ cnt, int* __restrict__ start,
    int* __restrict__ cursor, int N)
{
    __shared__ int wsum[16];
    __shared__ int s_carry;
    const int tid = threadIdx.x, wave = tid >> 6, lane = tid & 63;
    if (tid == 0) s_carry = 0;
    __syncthreads();
    for (int base = 0; base < N; base += 1024) {
        const int i = base + tid;
        const int v = (i < N) ? cnt[i] : 0;
        int x = v;                                  // inclusive intra-wave scan
#pragma unroll
        for (int d = 1; d < 64; d <<= 1) {
            const int y = __shfl_up(x, d, 64);
            if (lane >= d) x += y;
        }
        if (lane == 63) wsum[wave] = x;
        __syncthreads();
        if (wave == 0 && lane < 16) {
            int w = wsum[lane];
#pragma unroll
            for (int d = 1; d < 16; d <<= 1) {
                const int y = __shfl_up(w, d, 64);
                if (lane >= d) w += y;              // lanes 16..63 inactive
            }
            wsum[lane] = w;                         // inclusive wave-prefix
        }
        __syncthreads();
        const int woff = (wave == 0) ? 0 : wsum[wave - 1];
        const int carry = s_carry;
        if (i < N) {
            const int s = carry + woff + x - v;     // exclusive
            start[i] = s;
            cursor[i] = s;
        }
        __syncthreads();
        if (tid == 0) s_carry = carry + wsum[15];
        __syncthreads();
    }
    if (tid == 0) start[N] = s_carry;
}

// ===================== edge_k: K-side TP + dot + softmax terms =====================
// LDS: bf16 weights 20 KB (w4/w5 interleaved per (j,i)), xs pairs 16 KB,
//      xv pairs 24 KB = 61440 B -> 2 blocks/CU.
__global__ __launch_bounds__(BS) void edge_k(
    const float* __restrict__ node_ft,
    const int*   __restrict__ ei,
    const float* __restrict__ edge_sh,
    const float* __restrict__ edge_scalars,
    const float* __restrict__ fck_w1,
    const float* __restrict__ fck_w2,
    const float* __restrict__ qd,
    int*   __restrict__ cursor,
    float* __restrict__ exbuf,              // [E] CSR order
    float* __restrict__ sabuf,              // [E] edge order
    int*   __restrict__ posbuf,             // [E] edge order
    const int* __restrict__ flag,
    int N, int E)
{
    __shared__ __align__(16) unsigned short sk[32 * 320];   // 20 KB bf16
    __shared__ unsigned s_xs[16][BS];                       // 16 KB (e0 lo, e1 hi)
    __shared__ unsigned s_xv[3][8][BS];                     // 24 KB

    const int tid = threadIdx.x;
    // Stage weights bf16; interleave w4/w5 per (j,i) so tk4/5 read one uint4.
    for (int idx = tid; idx < 32 * 320; idx += BS) {
        const int j = idx / 320;
        const int c = idx - j * 320;
        int src;
        if (c < 256) src = c;
        else {
            const int i = (c - 256) >> 3, r = (c - 256) & 7;
            src = (r < 4) ? (256 + i*4 + r) : (288 + i*4 + (r - 4));
        }
        sk[idx] = f2b(fck_w2[j * 320 + src]);
    }

    const int e0 = blockIdx.x * EPB + tid;
    const bool v1 = (e0 + BS < E);
    const int e1 = e0 + BS;
    const int e1c = v1 ? e1 : ((e0 < E) ? e0 : 0);
    const int e0c = (e0 < E) ? e0 : 0;

    const int is64 = *flag;
    const int snd0 = is64 ? ei[2*e0c]       : ei[e0c];
    const int rcv0 = is64 ? ei[2*(E + e0c)] : ei[E + e0c];
    const int snd1 = is64 ? ei[2*e1c]       : ei[e1c];
    const int rcv1 = is64 ? ei[2*(E + e1c)] : ei[E + e1c];

    int pos0 = 0, pos1 = 0;
    if (e0 < E) pos0 = atomicAdd(cursor + rcv0, 1);   // early: hide under staging
    if (v1)     pos1 = atomicAdd(cursor + rcv1, 1);

    const float4 s40 = *(const float4*)(edge_sh + (size_t)e0c * 4);
    const float4 s41 = *(const float4*)(edge_sh + (size_t)e1c * 4);
    const float sh_s0 = s40.x, sh_s1 = s41.x;
    const float sh_v0[3] = {s40.y, s40.z, s40.w};
    const float sh_v1[3] = {s41.y, s41.z, s41.w};

    {
        const float4* p0 = (const float4*)(node_ft + (size_t)snd0 * 40);
        const float4* p1 = (const float4*)(node_ft + (size_t)snd1 * 40);
        float xb0[40], xb1[40];
#pragma unroll
        for (int t = 0; t < 10; ++t) {
            const float4 a = p0[t], b = p1[t];
            xb0[4*t+0]=a.x; xb0[4*t+1]=a.y; xb0[4*t+2]=a.z; xb0[4*t+3]=a.w;
            xb1[4*t+0]=b.x; xb1[4*t+1]=b.y; xb1[4*t+2]=b.z; xb1[4*t+3]=b.w;
        }
#pragma unroll
        for (int i = 0; i < 16; ++i) s_xs[i][tid] = pk2(xb0[i], xb1[i]);
#pragma unroll
        for (int i = 0; i < 8; ++i)
#pragma unroll
            for (int c = 0; c < 3; ++c)
                s_xv[c][i][tid] = pk2(xb0[16 + i*3 + c], xb1[16 + i*3 + c]);
    }
    __syncthreads();
    if (e0 >= E) return;   // no barriers below

    float es0[16], es1[16];
    {
        const float4* a0 = (const float4*)(edge_scalars + (size_t)e0c * 16);
        const float4* a1 = (const float4*)(edge_scalars + (size_t)e1c * 16);
#pragma unroll
        for (int t = 0; t < 4; ++t) {
            const float4 a = a0[t], b = a1[t];
            es0[4*t+0]=a.x; es0[4*t+1]=a.y; es0[4*t+2]=a.z; es0[4*t+3]=a.w;
            es1[4*t+0]=b.x; es1[4*t+1]=b.y; es1[4*t+2]=b.z; es1[4*t+3]=b.w;
        }
    }
    float hk0[32], hk1[32];
#pragma unroll
    for (int j = 0; j < 32; ++j) {
        float a = 0.f, b = 0.f;
#pragma unroll
        for (int t = 0; t < 16; ++t) {
            const float w = fck_w1[t*32 + j];
            a += es0[t] * w; b += es1[t] * w;
        }
        hk0[j] = silu_f(a * 0.25f);
        hk1[j] = silu_f(b * 0.25f);
    }

    // tk1 (xs->scalar, o=8) + tk3 (xs->vec, o=4)
    float K10[8] = {}, K11[8] = {}, K30[4] = {}, K31[4] = {};
#pragma unroll 1
    for (int i = 0; i < 16; ++i) {
        const unsigned xp = s_xs[i][tid];
        const float x0 = bl(xp), x1 = bh(xp);
        const unsigned short* w1p = sk + i*8;
        const unsigned short* w3p = sk + 192 + i*4;
#pragma unroll
        for (int j = 0; j < 32; ++j) {
            const float t0 = x0 * hk0[j], t1 = x1 * hk1[j];
            const uint4 a = *(const uint4*)(w1p + j*320);
            const uint2 c = *(const uint2*)(w3p + j*320);
            float w[8]; up8(a, w);
            float u[4]; up4(c, u);
#pragma unroll
            for (int o = 0; o < 8; ++o) { K10[o] += t0*w[o]; K11[o] += t1*w[o]; }
#pragma unroll
            for (int o = 0; o < 4; ++o) { K30[o] += t0*u[o]; K31[o] += t1*u[o]; }
        }
    }

    // tk2 (vv-dot path)
    float K20[8] = {}, K21[8] = {};
    const float c3 = 0.57735026918962576f;
    const float a00 = sh_v0[0]*c3, a01 = sh_v0[1]*c3, a02 = sh_v0[2]*c3;
    const float a10 = sh_v1[0]*c3, a11 = sh_v1[1]*c3, a12 = sh_v1[2]*c3;
#pragma unroll 1
    for (int i = 0; i < 8; ++i) {
        const unsigned b0 = s_xv[0][i][tid], b1 = s_xv[1][i][tid], b2 = s_xv[2][i][tid];
        const float p0 = bl(b0)*a00 + bl(b1)*a01 + bl(b2)*a02;
        const float p1 = bh(b0)*a10 + bh(b1)*a11 + bh(b2)*a12;
        const unsigned short* w2p = sk + 128 + i*8;
#pragma unroll
        for (int j = 0; j < 32; ++j) {
            const float t0 = p0 * hk0[j], t1 = p1 * hk1[j];
            const uint4 a = *(const uint4*)(w2p + j*320);
            float w[8]; up8(a, w);
#pragma unroll
            for (int o = 0; o < 8; ++o) { K20[o] += t0*w[o]; K21[o] += t1*w[o]; }
        }
    }

    // tk4/tk5: hoist j-contraction per i, apply xv (shs & cross folded in)
    float KV0[12] = {}, KV1[12] = {};
    const float c7 = 0.70710678118654752f;
#pragma unroll 1
    for (int i = 0; i < 8; ++i) {
        const unsigned b0 = s_xv[0][i][tid], b1 = s_xv[1][i][tid], b2 = s_xv[2][i][tid];
        const float x00 = bl(b0), x01 = bl(b1), x02 = bl(b2);
        const float x10 = bh(b0), x11 = bh(b1), x12 = bh(b2);
        float W40[4] = {}, W41[4] = {}, W50[4] = {}, W51[4] = {};
        const unsigned short* wp = sk + 256 + i*8;
#pragma unroll
        for (int j = 0; j < 32; ++j) {
            const uint4 a = *(const uint4*)(wp + j*320);
            const float h0 = hk0[j], h1 = hk1[j];
            float w[8]; up8(a, w);
#pragma unroll
            for (int o = 0; o < 4; ++o) {
                W40[o] += h0*w[o];   W41[o] += h1*w[o];
                W50[o] += h0*w[4+o]; W51[o] += h1*w[4+o];
            }
        }
        const float s00 = sh_s0*x00, s01 = sh_s0*x01, s02 = sh_s0*x02;
        const float s10 = sh_s1*x10, s11 = sh_s1*x11, s12 = sh_s1*x12;
        const float cx00 = c7*(x01*sh_v0[2] - x02*sh_v0[1]);
        const float cx01 = c7*(x02*sh_v0[0] - x00*sh_v0[2]);
        const float cx02 = c7*(x00*sh_v0[1] - x01*sh_v0[0]);
        const float cx10 = c7*(x11*sh_v1[2] - x12*sh_v1[1]);
        const float cx11 = c7*(x12*sh_v1[0] - x10*sh_v1[2]);
        const float cx12 = c7*(x10*sh_v1[1] - x11*sh_v1[0]);
#pragma unroll
        for (int o = 0; o < 4; ++o) {
            KV0[o*3+0] += s00*W40[o] + cx00*W50[o];
            KV0[o*3+1] += s01*W40[o] + cx01*W50[o];
            KV0[o*3+2] += s02*W40[o] + cx02*W50[o];
            KV1[o*3+0] += s10*W41[o] + cx10*W51[o];
            KV1[o*3+1] += s11*W41[o] + cx11*W51[o];
            KV1[o*3+2] += s12*W41[o] + cx12*W51[o];
        }
    }

    float qd0[20], qd1[20];
    {
        const float4* r0p = (const float4*)(qd + (size_t)rcv0 * 20);
        const float4* r1p = (const float4*)(qd + (size_t)rcv1 * 20);
#pragma unroll
        for (int t = 0; t < 5; ++t) {
            const float4 a = r0p[t], b = r1p[t];
            qd0[4*t+0]=a.x; qd0[4*t+1]=a.y; qd0[4*t+2]=a.z; qd0[4*t+3]=a.w;
            qd1[4*t+0]=b.x; qd1[4*t+1]=b.y; qd1[4*t+2]=b.z; qd1[4*t+3]=b.w;
        }
    }
    float ds0 = 0.f, ds1 = 0.f;
#pragma unroll
    for (int o = 0; o < 8; ++o) {
        ds0 += qd0[o] * (sh_s0*K10[o] + K20[o]);
        ds1 += qd1[o] * (sh_s1*K11[o] + K21[o]);
    }
    float dv0 = 0.f, dv1 = 0.f;
#pragma unroll
    for (int o = 0; o < 4; ++o)
#pragma unroll
        for (int c = 0; c < 3; ++c) {
            dv0 += qd0[8 + o*3 + c] * (K30[o]*sh_v0[c] + KV0[o*3+c]);
            dv1 += qd1[8 + o*3 + c] * (K31[o]*sh_v1[c] + KV1[o*3+c]);
        }
    const float dot0 = ds0 * 4.0343567508008e-3f + dv0 * 2.0171788261497e-3f;
    const float dot1 = ds1 * 4.0343567508008e-3f + dv1 * 2.0171788261497e-3f;
    const float sa0 = __expf(0.5f * dot0);
    const float sa1 = __expf(0.5f * dot1);
    exbuf[pos0] = sa0 * sa0; sabuf[e0] = sa0; posbuf[e0] = pos0;
    if (v1) { exbuf[pos1] = sa1 * sa1; sabuf[e1] = sa1; posbuf[e1] = pos1; }
}

// ===================== edge_v_a: V scalar outputs (cols [0,384)) =====================
// LDS: bf16 weights 24 KB, xs f32 pairs 32 KB (pre-scaled by shs), pv pairs 8 KB
//      = 65536 B -> 2 blocks/CU. Scalar path keeps one bf16 factor (W only).
__global__ __launch_bounds__(BS) void edge_v_a(
    const float* __restrict__ node_ft,
    const int*   __restrict__ ei,
    const float* __restrict__ edge_sh,
    const float* __restrict__ edge_scalars,
    const float* __restrict__ fcv_w1,
    const float* __restrict__ fcv_w2,
    const float* __restrict__ sabuf,
    const int*   __restrict__ posbuf,
    float* __restrict__ vbuf,               // [E,40]
    const int* __restrict__ flag,
    int E)
{
    __shared__ __align__(16) unsigned short sW[32 * 384];   // 24 KB bf16
    __shared__ float2 s_xs[16][BS];                         // 32 KB f32 pairs
    __shared__ unsigned s_pv[8][BS];                        // 8 KB bf16 pairs

    const int tid = threadIdx.x;
    for (int idx = tid; idx < 32 * 384; idx += BS) {
        const int j = idx / 384;
        const int c = idx - j * 384;
        sW[idx] = f2b(fcv_w2[j * 640 + c]);
    }

    const int e0 = blockIdx.x * EPB + tid;
    const bool v1 = (e0 + BS < E);
    const int e1 = e0 + BS;
    const int e1c = v1 ? e1 : ((e0 < E) ? e0 : 0);
    const int e0c = (e0 < E) ? e0 : 0;

    const int is64 = *flag;
    const int snd0 = is64 ? ei[2*e0c] : ei[e0c];
    const int snd1 = is64 ? ei[2*e1c] : ei[e1c];

    const float4 s40 = *(const float4*)(edge_sh + (size_t)e0c * 4);
    const float4 s41 = *(const float4*)(edge_sh + (size_t)e1c * 4);

    {
        const float4* p0 = (const float4*)(node_ft + (size_t)snd0 * 40);
        const float4* p1 = (const float4*)(node_ft + (size_t)snd1 * 40);
        float xb0[40], xb1[40];
#pragma unroll
        for (int t = 0; t < 10; ++t) {
            const float4 a = p0[t], b = p1[t];
            xb0[4*t+0]=a.x; xb0[4*t+1]=a.y; xb0[4*t+2]=a.z; xb0[4*t+3]=a.w;
            xb1[4*t+0]=b.x; xb1[4*t+1]=b.y; xb1[4*t+2]=b.z; xb1[4*t+3]=b.w;
        }
#pragma unroll
        for (int i = 0; i < 16; ++i) {
            float2 xx; xx.x = xb0[i] * s40.x; xx.y = xb1[i] * s41.x;  // fold shs
            s_xs[i][tid] = xx;
        }
        const float c3 = 0.57735026918962576f;
#pragma unroll
        for (int i = 0; i < 8; ++i) {
            const float pv0 = (xb0[16+i*3]*s40.y + xb0[17+i*3]*s40.z + xb0[18+i*3]*s40.w) * c3;
            const float pv1 = (xb1[16+i*3]*s41.y + xb1[17+i*3]*s41.z + xb1[18+i*3]*s41.w) * c3;
            s_pv[i][tid] = pk2(pv0, pv1);
        }
    }
    __syncthreads();
    if (e0 >= E) return;

    float es0[16], es1[16];
    {
        const float4* a0 = (const float4*)(edge_scalars + (size_t)e0c * 16);
        const float4* a1 = (const float4*)(edge_scalars + (size_t)e1c * 16);
#pragma unroll
        for (int t = 0; t < 4; ++t) {
            const float4 a = a0[t], b = a1[t];
            es0[4*t+0]=a.x; es0[4*t+1]=a.y; es0[4*t+2]=a.z; es0[4*t+3]=a.w;
            es1[4*t+0]=b.x; es1[4*t+1]=b.y; es1[4*t+2]=b.z; es1[4*t+3]=b.w;
        }
    }
    float hv0[32], hv1[32];
#pragma unroll
    for (int j = 0; j < 32; ++j) {
        float a = 0.f, b = 0.f;
#pragma unroll
        for (int t = 0; t < 16; ++t) {
            const float w = fcv_w1[t*32 + j];
            a += es0[t] * w; b += es1[t] * w;
        }
        hv0[j] = silu_f(a * 0.25f);
        hv1[j] = silu_f(b * 0.25f);
    }

    float A0[16] = {}, A1[16] = {};
#pragma unroll 1
    for (int i = 0; i < 16; ++i) {
        const float2 xx = s_xs[i][tid];
        const float x0 = xx.x, x1 = xx.y;
        const unsigned short* wp = sW + i*16;
#pragma unroll
        for (int j = 0; j < 32; ++j) {
            const float t0 = x0 * hv0[j], t1 = x1 * hv1[j];
            const uint4 a = *(const uint4*)(wp + j*384);
            const uint4 b = *(const uint4*)(wp + j*384 + 8);
            float w[16]; up8(a, w); up8(b, w + 8);
#pragma unroll
            for (int o = 0; o < 16; ++o) { A0[o] += t0*w[o]; A1[o] += t1*w[o]; }
        }
    }
    float B0[16] = {}, B1[16] = {};
#pragma unroll 1
    for (int i = 0; i < 8; ++i) {
        const unsigned pp = s_pv[i][tid];
        const float p0 = bl(pp), p1 = bh(pp);
        const unsigned short* wp = sW + 256 + i*16;
#pragma unroll
        for (int j = 0; j < 32; ++j) {
            const float t0 = p0 * hv0[j], t1 = p1 * hv1[j];
            const uint4 a = *(const uint4*)(wp + j*384);
            const uint4 b = *(const uint4*)(wp + j*384 + 8);
            float w[16]; up8(a, w); up8(b, w + 8);
#pragma unroll
            for (int o = 0; o < 16; ++o) { B0[o] += t0*w[o]; B1[o] += t1*w[o]; }
        }
    }

    const float cs = 0.03608439182435161f;   // (1/sqrt32)*(1/sqrt24)
    const float sa0 = sabuf[e0];
    const int pos0 = posbuf[e0];
    float4* vp0 = (float4*)(vbuf + (size_t)pos0 * 40);
#pragma unroll
    for (int t = 0; t < 4; ++t) {
        float4 r;
        r.x = sa0 * (A0[4*t+0] + B0[4*t+0]) * cs;
        r.y = sa0 * (A0[4*t+1] + B0[4*t+1]) * cs;
        r.z = sa0 * (A0[4*t+2] + B0[4*t+2]) * cs;
        r.w = sa0 * (A0[4*t+3] + B0[4*t+3]) * cs;
        vp0[t] = r;
    }
    if (v1) {
        const float sa1 = sabuf[e1];
        const int pos1 = posbuf[e1];
        float4* vp1 = (float4*)(vbuf + (size_t)pos1 * 40);
#pragma unroll
        for (int t = 0; t < 4; ++t) {
            float4 r;
            r.x = sa1 * (A1[4*t+0] + B1[4*t+0]) * cs;
            r.y = sa1 * (A1[4*t+1] + B1[4*t+1]) * cs;
            r.z = sa1 * (A1[4*t+2] + B1[4*t+2]) * cs;
            r.w = sa1 * (A1[4*t+3] + B1[4*t+3]) * cs;
            vp1[t] = r;
        }
    }
}

// ===================== edge_v_b: V vector outputs (cols [384,640)) =====================
// LDS: bf16 weights 16 KB, xs pairs 8 KB, xv pairs 24 KB = 49152 B -> 3 blocks/CU.
__global__ __launch_bounds__(BS) void edge_v_b(
    const float* __restrict__ node_ft,
    const int*   __restrict__ ei,
    const float* __restrict__ edge_sh,
    const float* __restrict__ edge_scalars,
    const float* __restrict__ fcv_w1,
    const float* __restrict__ fcv_w2,
    const float* __restrict__ sabuf,
    const int*   __restrict__ posbuf,
    float* __restrict__ vbuf,               // [E,40]
    const int* __restrict__ flag,
    int E)
{
    __shared__ __align__(16) unsigned short sv[32 * 256];   // 16 KB bf16 (local = global-384)
    __shared__ unsigned s_xs[16][BS];                       // 8 KB
    __shared__ unsigned s_xv[3][8][BS];                     // 24 KB

    const int tid = threadIdx.x;
    for (int idx = tid; idx < 32 * 256; idx += BS) {
        const int j = idx >> 8;
        const int c = idx & 255;
        sv[idx] = f2b(fcv_w2[j * 640 + 384 + c]);
    }

    const int e0 = blockIdx.x * EPB + tid;
    const bool v1 = (e0 + BS < E);
    const int e1 = e0 + BS;
    const int e1c = v1 ? e1 : ((e0 < E) ? e0 : 0);
    const int e0c = (e0 < E) ? e0 : 0;

    const int is64 = *flag;
    const int snd0 = is64 ? ei[2*e0c] : ei[e0c];
    const int snd1 = is64 ? ei[2*e1c] : ei[e1c];

    const float4 s40 = *(const float4*)(edge_sh + (size_t)e0c * 4);
    const float4 s41 = *(const float4*)(edge_sh + (size_t)e1c * 4);
    const float sh_s0 = s40.x, sh_s1 = s41.x;
    const float sh_v0[3] = {s40.y, s40.z, s40.w};
    const float sh_v1[3] = {s41.y, s41.z, s41.w};

    {
        const float4* p0 = (const float4*)(node_ft + (size_t)snd0 * 40);
        const float4* p1 = (const float4*)(node_ft + (size_t)snd1 * 40);
        float xb0[40], xb1[40];
#pragma unroll
        for (int t = 0; t < 10; ++t) {
            const float4 a = p0[t], b = p1[t];
            xb0[4*t+0]=a.x; xb0[4*t+1]=a.y; xb0[4*t+2]=a.z; xb0[4*t+3]=a.w;
            xb1[4*t+0]=b.x; xb1[4*t+1]=b.y; xb1[4*t+2]=b.z; xb1[4*t+3]=b.w;
        }
#pragma unroll
        for (int i = 0; i < 16; ++i) s_xs[i][tid] = pk2(xb0[i], xb1[i]);
#pragma unroll
        for (int i = 0; i < 8; ++i)
#pragma unroll
            for (int c = 0; c < 3; ++c)
                s_xv[c][i][tid] = pk2(xb0[16 + i*3 + c], xb1[16 + i*3 + c]);
    }
    __syncthreads();
    if (e0 >= E) return;

    float es0[16], es1[16];
    {
        const float4* a0 = (const float4*)(edge_scalars + (size_t)e0c * 16);
        const float4* a1 = (const float4*)(edge_scalars + (size_t)e1c * 16);
#pragma unroll
        for (int t = 0; t < 4; ++t) {
            const float4 a = a0[t], b = a1[t];
            es0[4*t+0]=a.x; es0[4*t+1]=a.y; es0[4*t+2]=a.z; es0[4*t+3]=a.w;
            es1[4*t+0]=b.x; es1[4*t+1]=b.y; es1[4*t+2]=b.z; es1[4*t+3]=b.w;
        }
    }
    float hv0[32], hv1[32];
#pragma unroll
    for (int j = 0; j < 32; ++j) {
        float a = 0.f, b = 0.f;
#pragma unroll
        for (int t = 0; t < 16; ++t) {
            const float w = fcv_w1[t*32 + j];
            a += es0[t] * w; b += es1[t] * w;
        }
        hv0[j] = silu_f(a * 0.25f);
        hv1[j] = silu_f(b * 0.25f);
    }

    // tv3 (xs (x) shv path): scalar accumulation, shv applied in epilogue
    float T30[8] = {}, T31[8] = {};
#pragma unroll 1
    for (int i = 0; i < 16; ++i) {
        const unsigned xp = s_xs[i][tid];
        const float x0 = bl(xp), x1 = bh(xp);
        const unsigned short* wp = sv + i*8;
#pragma unroll
        for (int j = 0; j < 32; ++j) {
            const float t0 = x0 * hv0[j], t1 = x1 * hv1[j];
            const uint4 a = *(const uint4*)(wp + j*256);
            float w[8]; up8(a, w);
#pragma unroll
            for (int o = 0; o < 8; ++o) { T30[o] += t0*w[o]; T31[o] += t1*w[o]; }
        }
    }

    // tv4/tv5: hoist j-contraction per i, accumulate straight into row (shs, cross folded)
    float R0[24] = {}, R1[24] = {};
    const float c7 = 0.70710678118654752f;
#pragma unroll 1
    for (int i = 0; i < 8; ++i) {
        const unsigned b0 = s_xv[0][i][tid], b1 = s_xv[1][i][tid], b2 = s_xv[2][i][tid];
        const float x00 = bl(b0), x01 = bl(b1), x02 = bl(b2);
        const float x10 = bh(b0), x11 = bh(b1), x12 = bh(b2);
        float W40[8] = {}, W41[8] = {}, W50[8] = {}, W51[8] = {};
        const unsigned short* w4p = sv + 128 + i*8;
        const unsigned short* w5p = sv + 192 + i*8;
#pragma unroll
        for (int j = 0; j < 32; ++j) {
            const uint4 a = *(const uint4*)(w4p + j*256);
            const uint4 b = *(const uint4*)(w5p + j*256);
            const float h0 = hv0[j], h1 = hv1[j];
            float w[8], u[8]; up8(a, w); up8(b, u);
#pragma unroll
            for (int o = 0; o < 8; ++o) {
                W40[o] += h0*w[o]; W41[o] += h1*w[o];
                W50[o] += h0*u[o]; W51[o] += h1*u[o];
            }
        }
        const float s00 = sh_s0*x00, s01 = sh_s0*x01, s02 = sh_s0*x02;
        const float s10 = sh_s1*x10, s11 = sh_s1*x11, s12 = sh_s1*x12;
        const float cx00 = c7*(x01*sh_v0[2] - x02*sh_v0[1]);
        const float cx01 = c7*(x02*sh_v0[0] - x00*sh_v0[2]);
        const float cx02 = c7*(x00*sh_v0[1] - x01*sh_v0[0]);
        const float cx10 = c7*(x11*sh_v1[2] - x12*sh_v1[1]);
        const float cx11 = c7*(x12*sh_v1[0] - x10*sh_v1[2]);
        const float cx12 = c7*(x10*sh_v1[1] - x11*sh_v1[0]);
#pragma unroll
        for (int o = 0; o < 8; ++o) {
            R0[o*3+0] += s00*W40[o] + cx00*W50[o];
            R0[o*3+1] += s01*W40[o] + cx01*W50[o];
            R0[o*3+2] += s02*W40[o] + cx02*W50[o];
            R1[o*3+0] += s10*W41[o] + cx10*W51[o];
            R1[o*3+1] += s11*W41[o] + cx11*W51[o];
            R1[o*3+2] += s12*W41[o] + cx12*W51[o];
        }
    }

    const float sc = 0.03125f;               // (1/sqrt32)*(1/sqrt32)
    {
        const float sa0 = sabuf[e0];
        const int pos0 = posbuf[e0];
        float row[24];
#pragma unroll
        for (int o = 0; o < 8; ++o)
#pragma unroll
            for (int c = 0; c < 3; ++c)
                row[o*3+c] = sa0 * (T30[o]*sh_v0[c] + R0[o*3+c]) * sc;
        float4* vp = (float4*)(vbuf + (size_t)pos0 * 40 + 16);
#pragma unroll
        for (int t = 0; t < 6; ++t) {
            float4 r; r.x = row[4*t+0]; r.y = row[4*t+1]; r.z = row[4*t+2]; r.w = row[4*t+3];
            vp[t] = r;
        }
    }
    if (v1) {
        const float sa1 = sabuf[e1];
        const int pos1 = posbuf[e1];
        float row[24];
#pragma unroll
        for (int o = 0; o < 8; ++o)
#pragma unroll
            for (int c = 0; c < 3; ++c)
                row[o*3+c] = sa1 * (T31[o]*sh_v1[c] + R1[o*3+c]) * sc;
        float4* vp = (float4*)(vbuf + (size_t)pos1 * 40 + 16);
#pragma unroll
        for (int t = 0; t < 6; ++t) {
            float4 r; r.x = row[4*t+0]; r.y = row[4*t+1]; r.z = row[4*t+2]; r.w = row[4*t+3];
            vp[t] = r;
        }
    }
}

__global__ __launch_bounds__(256) void node_reduce(
    const int*   __restrict__ start,
    const float* __restrict__ exbuf,
    const float* __restrict__ vbuf,
    float* __restrict__ out, int N)
{
    const int wave = threadIdx.x >> 6;
    const int lane = threadIdx.x & 63;
    const int n = blockIdx.x * 4 + wave;
    if (n >= N) return;
    const int r0 = start[n], r1 = start[n + 1];
    float z = 0.f, comp = 0.f;
    for (int r = r0; r < r1; ++r) {
        z += exbuf[r];
        if (lane < 40) comp += vbuf[(size_t)r * 40 + lane];
    }
    if (lane < 40)
        out[(size_t)n * 40 + lane] = (z > 0.f) ? comp * rsqrtf(z) : 0.f;
}

extern "C" void kernel_launch(void* const* d_in, const int* in_sizes, int n_in,
                              void* d_out, int out_size, void* d_ws, size_t ws_size,
                              hipStream_t stream) {
    const float* node_ft      = (const float*)d_in[0];
    const int*   edge_index   = (const int*)  d_in[1];
    const float* edge_sh      = (const float*)d_in[2];
    const float* edge_scalars = (const float*)d_in[3];
    const float* w_q_s        = (const float*)d_in[4];
    const float* w_q_v        = (const float*)d_in[5];
    const float* fck_w1       = (const float*)d_in[6];
    const float* fck_w2       = (const float*)d_in[7];
    const float* fcv_w1       = (const float*)d_in[8];
    const float* fcv_w2       = (const float*)d_in[9];
    const float* wdot_s       = (const float*)d_in[10];
    const float* wdot_v       = (const float*)d_in[11];

    const int N = in_sizes[0] / 40;
    const int E = in_sizes[2] / 4;

    float* ws    = (float*)d_ws;
    float* qd    = ws;                               // N*20
    int*   cnt   = (int*)(ws + (size_t)N * 20);      // N
    int*   start = cnt + N;                          // N+1
    int*   curs  = start + N + 1;                    // N
    int*   flg   = curs + N;                         // 1
    size_t off   = (size_t)N * 20 + N + (N + 1) + N + 1;
    off = (off + 3) & ~(size_t)3;                    // 16B align
    float* exbuf  = ws + off;                        // E
    float* sabuf  = exbuf + E;                       // E
    int*   posbuf = (int*)(sabuf + E);               // E
    float* vbuf   = (float*)(posbuf + E);            // E*40 (E%4==0 -> aligned)

    float* out = (float*)d_out;

    const int EB = (E + EPB - 1) / EPB;

    hipLaunchKernelGGL(node_pre, dim3((N + 255) / 256), dim3(256), 0, stream,
                       node_ft, edge_index, w_q_s, w_q_v, wdot_s, wdot_v,
                       qd, cnt, flg, N, E);
    hipLaunchKernelGGL(count_edges, dim3((E + 255) / 256), dim3(256), 0, stream,
                       edge_index, cnt, flg, E);
    hipLaunchKernelGGL(scan_kernel, dim3(1), dim3(1024), 0, stream,
                       cnt, start, curs, N);
    hipLaunchKernelGGL(edge_k, dim3(EB), dim3(BS), 0, stream,
                       node_ft, edge_index, edge_sh, edge_scalars,
                       fck_w1, fck_w2, qd, curs, exbuf, sabuf, posbuf, flg, N, E);
    hipLaunchKernelGGL(edge_v_a, dim3(EB), dim3(BS), 0, stream,
                       node_ft, edge_index, edge_sh, edge_scalars,
                       fcv_w1, fcv_w2, sabuf, posbuf, vbuf, flg, E);
    hipLaunchKernelGGL(edge_v_b, dim3(EB), dim3(BS), 0, stream,
                       node_ft, edge_index, edge_sh, edge_scalars,
                       fcv_w1, fcv_w2, sabuf, posbuf, vbuf, flg, E);
    hipLaunchKernelGGL(node_reduce, dim3((N + 3) / 4), dim3(256), 0, stream,
                       start, exbuf, vbuf, out, N);
}